// Round 1
// baseline (573.571 us; speedup 1.0000x reference)
//
#include <hip/hip_runtime.h>
#include <math.h>

#define NTOK 4096
#define DIM 256
#define NHID 64
#define NHEADS 4
#define KSEL 6            // K+1
#define ALPHA_LR 0.2f
#define LNEPS 1e-5f
#define BIGN 768          // xm(256) | xr(256) | Wh(4*64)
#define JSPLIT 8
#define JCHUNK (NTOK / JSPLIT)   // 512

__device__ __forceinline__ float f4get(const float4& v, int k) {
    return (k == 0) ? v.x : (k == 1) ? v.y : (k == 2) ? v.z : v.w;
}

// ---------------- repack: BigB[256][768] = [Wm | Wr | W heads], BigBias[768] ----
__global__ void repack_kernel(const float* __restrict__ Wm, const float* __restrict__ bm,
                              const float* __restrict__ W,  const float* __restrict__ Wr,
                              const float* __restrict__ br,
                              float* __restrict__ BigB, float* __restrict__ BigBias) {
    int tid = blockIdx.x * blockDim.x + threadIdx.x;
    int total = DIM * BIGN;
    for (int e = tid; e < total; e += gridDim.x * blockDim.x) {
        int k = e / BIGN, col = e - k * BIGN;
        float v;
        if (col < 256)      v = Wm[k * 256 + col];
        else if (col < 512) v = Wr[k * 256 + (col - 256)];
        else {
            int c = col - 512;
            int h = c >> 6, d = c & 63;
            v = W[(h * DIM + k) * NHID + d];
        }
        BigB[e] = v;
    }
    if (tid < BIGN) {
        float b = 0.f;
        if (tid < 256)      b = bm[tid];
        else if (tid < 512) b = br[tid - 256];
        BigBias[tid] = b;
    }
}

// ---------------- GEMM: BigC[4096][768] = x[4096][256] @ BigB + BigBias --------
#define GEMM_SA 36
__global__ __launch_bounds__(256) void gemm_kernel(const float* __restrict__ A,
        const float* __restrict__ B, const float* __restrict__ bias,
        float* __restrict__ C) {
    __shared__ float As[64][GEMM_SA];   // [row][k]  (32 k used, pad to 36)
    __shared__ float Bs[32][64];        // [k][j]
    const int t  = threadIdx.x;
    const int tx = t & 15, ty = t >> 4;
    const int i0 = blockIdx.x * 64;
    const int j0 = blockIdx.y * 64;
    float c[4][4] = {};
    for (int kc = 0; kc < DIM / 32; ++kc) {
        __syncthreads();
        #pragma unroll
        for (int p = 0; p < 2; ++p) {
            int f  = t + p * 256;
            int ra = f >> 3, ka = (f & 7) * 4;
            *(float4*)&As[ra][ka] =
                *(const float4*)&A[(size_t)(i0 + ra) * DIM + kc * 32 + ka];
            int kb = f >> 4, jb = (f & 15) * 4;
            *(float4*)&Bs[kb][jb] =
                *(const float4*)&B[(size_t)(kc * 32 + kb) * BIGN + j0 + jb];
        }
        __syncthreads();
        #pragma unroll
        for (int kq = 0; kq < 8; ++kq) {
            float4 a4[4], b4[4];
            #pragma unroll
            for (int ii = 0; ii < 4; ++ii) a4[ii] = *(const float4*)&As[ty * 4 + ii][kq * 4];
            #pragma unroll
            for (int kk = 0; kk < 4; ++kk) b4[kk] = *(const float4*)&Bs[kq * 4 + kk][tx * 4];
            #pragma unroll
            for (int ii = 0; ii < 4; ++ii)
                #pragma unroll
                for (int kk = 0; kk < 4; ++kk)
                    #pragma unroll
                    for (int jj = 0; jj < 4; ++jj)
                        c[ii][jj] = fmaf(f4get(a4[ii], kk), f4get(b4[kk], jj), c[ii][jj]);
        }
    }
    #pragma unroll
    for (int ii = 0; ii < 4; ++ii) {
        int r = i0 + ty * 4 + ii;
        float4 bv = *(const float4*)&bias[j0 + tx * 4];
        float4 o;
        o.x = c[ii][0] + bv.x; o.y = c[ii][1] + bv.y;
        o.z = c[ii][2] + bv.z; o.w = c[ii][3] + bv.w;
        *(float4*)&C[(size_t)r * BIGN + j0 + tx * 4] = o;
    }
}

// ---------------- sq[n], e1[h][n], e2[h][n] ------------------------------------
__global__ __launch_bounds__(256) void sq_e_kernel(const float* __restrict__ BigC,
        const float* __restrict__ a, float* __restrict__ sq,
        float* __restrict__ e1, float* __restrict__ e2) {
    const int n = blockIdx.x;
    const int t = threadIdx.x;
    __shared__ float red[256];
    float xm = BigC[(size_t)n * BIGN + t];
    red[t] = xm * xm;
    __syncthreads();
    #pragma unroll
    for (int s = 128; s > 0; s >>= 1) { if (t < s) red[t] += red[t + s]; __syncthreads(); }
    if (t == 0) sq[n] = red[0];
    const int h = t >> 6, d = t & 63;
    float wh = BigC[(size_t)n * BIGN + 512 + t];
    float v1 = wh * a[h * 128 + d];
    float v2 = wh * a[h * 128 + 64 + d];
    #pragma unroll
    for (int s = 32; s > 0; s >>= 1) {
        v1 += __shfl_down(v1, s, 64);
        v2 += __shfl_down(v2, s, 64);
    }
    if (d == 0) { e1[h * NTOK + n] = v1; e2[h * NTOK + n] = v2; }
}

// ---------------- distance GEMM + fused per-row top-6 --------------------------
#define DS_SA 68
__global__ __launch_bounds__(256) void dist_topk_kernel(const float* __restrict__ BigC,
        const float* __restrict__ sq, float* __restrict__ candD, int* __restrict__ candI) {
    __shared__ float As[64][DS_SA];   // [row i][k]
    __shared__ float Bs[64][DS_SA];   // [row j][k]
    __shared__ float Dsh[64][65];     // key tile [i][j]
    const int t  = threadIdx.x;
    const int tx = t & 15, ty = t >> 4;
    const int row0  = blockIdx.x * 64;
    const int jbase = blockIdx.y * JCHUNK;
    float bd[KSEL]; int bi[KSEL];
    #pragma unroll
    for (int k = 0; k < KSEL; ++k) { bd[k] = 3.0e38f; bi[k] = 0x7fffffff; }

    for (int jt = 0; jt < JCHUNK / 64; ++jt) {
        const int j0 = jbase + jt * 64;
        float c[4][4] = {};
        for (int kc = 0; kc < DIM / 64; ++kc) {
            __syncthreads();
            #pragma unroll
            for (int p = 0; p < 4; ++p) {
                int f = t + p * 256;
                int r = f >> 4, kq4 = (f & 15) * 4;
                *(float4*)&As[r][kq4] =
                    *(const float4*)&BigC[(size_t)(row0 + r) * BIGN + kc * 64 + kq4];
                *(float4*)&Bs[r][kq4] =
                    *(const float4*)&BigC[(size_t)(j0 + r) * BIGN + kc * 64 + kq4];
            }
            __syncthreads();
            #pragma unroll
            for (int kq = 0; kq < 16; ++kq) {
                float4 a4[4], b4[4];
                #pragma unroll
                for (int ii = 0; ii < 4; ++ii) a4[ii] = *(const float4*)&As[ty * 4 + ii][kq * 4];
                #pragma unroll
                for (int jj = 0; jj < 4; ++jj) b4[jj] = *(const float4*)&Bs[tx * 4 + jj][kq * 4];
                #pragma unroll
                for (int ii = 0; ii < 4; ++ii)
                    #pragma unroll
                    for (int jj = 0; jj < 4; ++jj)
                        #pragma unroll
                        for (int kk = 0; kk < 4; ++kk)
                            c[ii][jj] = fmaf(f4get(a4[ii], kk), f4get(b4[jj], kk), c[ii][jj]);
            }
        }
        __syncthreads();
        // key = sq_j - 2*dot  (sq_i is a row-constant shift: ordering-invariant)
        #pragma unroll
        for (int jj = 0; jj < 4; ++jj) {
            float sqj = sq[j0 + tx * 4 + jj];
            #pragma unroll
            for (int ii = 0; ii < 4; ++ii)
                Dsh[ty * 4 + ii][tx * 4 + jj] = sqj - 2.0f * c[ii][jj];
        }
        __syncthreads();
        if (t < 64) {
            #pragma unroll 4
            for (int jj = 0; jj < 64; ++jj) {
                float dv = Dsh[t][jj];
                int   j  = j0 + jj;
                if (dv < bd[5] || (dv == bd[5] && j < bi[5])) {
                    bool l4 = (dv < bd[4]) || (dv == bd[4] && j < bi[4]);
                    bool l3 = (dv < bd[3]) || (dv == bd[3] && j < bi[3]);
                    bool l2 = (dv < bd[2]) || (dv == bd[2] && j < bi[2]);
                    bool l1 = (dv < bd[1]) || (dv == bd[1] && j < bi[1]);
                    bool l0 = (dv < bd[0]) || (dv == bd[0] && j < bi[0]);
                    bd[5] = l4 ? bd[4] : dv;  bi[5] = l4 ? bi[4] : j;
                    if (l4) { bd[4] = l3 ? bd[3] : dv; bi[4] = l3 ? bi[3] : j; }
                    if (l3) { bd[3] = l2 ? bd[2] : dv; bi[3] = l2 ? bi[2] : j; }
                    if (l2) { bd[2] = l1 ? bd[1] : dv; bi[2] = l1 ? bi[1] : j; }
                    if (l1) { bd[1] = l0 ? bd[0] : dv; bi[1] = l0 ? bi[0] : j; }
                    if (l0) { bd[0] = dv;              bi[0] = j; }
                }
            }
        }
    }
    if (t < 64) {
        size_t base = ((size_t)(row0 + t) * JSPLIT + blockIdx.y) * KSEL;
        #pragma unroll
        for (int k = 0; k < KSEL; ++k) { candD[base + k] = bd[k]; candI[base + k] = bi[k]; }
    }
}

// ---------------- merge per-range top-6 -> global top-6 ------------------------
__global__ void merge_kernel(const float* __restrict__ candD, const int* __restrict__ candI,
                             int* __restrict__ idx6) {
    int row = blockIdx.x * blockDim.x + threadIdx.x;
    if (row >= NTOK) return;
    size_t base = (size_t)row * JSPLIT * KSEL;
    float lastD = -3.0e38f; int lastI = -1;
    #pragma unroll 1
    for (int k = 0; k < KSEL; ++k) {
        float bdv = 3.4e38f; int biv = 0x7fffffff;
        #pragma unroll 1
        for (int q = 0; q < JSPLIT * KSEL; ++q) {
            float dv = candD[base + q]; int iv = candI[base + q];
            bool after  = (dv > lastD) || (dv == lastD && iv > lastI);
            bool better = (dv < bdv)  || (dv == bdv  && iv < biv);
            if (after && better) { bdv = dv; biv = iv; }
        }
        idx6[row * KSEL + k] = biv;
        lastD = bdv; lastI = biv;
    }
}

// ---------------- attention + residual + LN + ELU + out projection -------------
__global__ __launch_bounds__(256) void final_kernel(const float* __restrict__ BigC,
        const float* __restrict__ e1, const float* __restrict__ e2,
        const int* __restrict__ idx6, const float* __restrict__ ln_g,
        const float* __restrict__ ln_b, const float* __restrict__ Wo,
        const float* __restrict__ bo, float* __restrict__ out) {
    const int i = blockIdx.x;
    const int t = threadIdx.x;
    const int h = t >> 6;
    __shared__ int sidx[KSEL];
    __shared__ float red[256];
    if (t < KSEL) sidx[t] = idx6[i * KSEL + t];
    __syncthreads();
    const float e1i = e1[h * NTOK + i];
    float ev[KSEL];
    float m = -3.0e38f;
    #pragma unroll
    for (int k = 0; k < KSEL; ++k) {
        float v = e1i + e2[h * NTOK + sidx[k]];
        v = (v > 0.f) ? v : ALPHA_LR * v;
        ev[k] = v;
        m = fmaxf(m, v);
    }
    float ssum = 0.f;
    #pragma unroll
    for (int k = 0; k < KSEL; ++k) { ev[k] = expf(ev[k] - m); ssum += ev[k]; }
    float agg = 0.f;
    #pragma unroll
    for (int k = 0; k < KSEL; ++k)
        agg += ev[k] * BigC[(size_t)sidx[k] * BIGN + 512 + t];
    agg /= ssum;
    float hv = agg + BigC[(size_t)i * BIGN + 256 + t];
    // LayerNorm over 256
    red[t] = hv; __syncthreads();
    #pragma unroll
    for (int s = 128; s > 0; s >>= 1) { if (t < s) red[t] += red[t + s]; __syncthreads(); }
    float mu = red[0] * (1.f / 256.f);
    __syncthreads();
    float dv = hv - mu;
    red[t] = dv * dv; __syncthreads();
    #pragma unroll
    for (int s = 128; s > 0; s >>= 1) { if (t < s) red[t] += red[t + s]; __syncthreads(); }
    float var = red[0] * (1.f / 256.f);
    __syncthreads();
    float nv  = dv / sqrtf(var + LNEPS) * ln_g[t] + ln_b[t];
    float act = (nv > 0.f) ? nv : expm1f(nv);
    // out = act @ Wo + bo  (two 256-length dots)
    red[t] = act * Wo[t * 2 + 0]; __syncthreads();
    #pragma unroll
    for (int s = 128; s > 0; s >>= 1) { if (t < s) red[t] += red[t + s]; __syncthreads(); }
    float o0 = red[0];
    __syncthreads();
    red[t] = act * Wo[t * 2 + 1]; __syncthreads();
    #pragma unroll
    for (int s = 128; s > 0; s >>= 1) { if (t < s) red[t] += red[t + s]; __syncthreads(); }
    if (t == 0) { out[i * 2 + 0] = o0 + bo[0]; out[i * 2 + 1] = red[0] + bo[1]; }
}

extern "C" void kernel_launch(void* const* d_in, const int* in_sizes, int n_in,
                              void* d_out, int out_size, void* d_ws, size_t ws_size,
                              hipStream_t stream) {
    (void)in_sizes; (void)n_in; (void)out_size; (void)ws_size;
    const float* x    = (const float*)d_in[0];
    const float* Wm   = (const float*)d_in[1];
    const float* bm   = (const float*)d_in[2];
    const float* W    = (const float*)d_in[3];
    const float* a    = (const float*)d_in[4];
    const float* Wr   = (const float*)d_in[5];
    const float* br   = (const float*)d_in[6];
    const float* ln_g = (const float*)d_in[7];
    const float* ln_b = (const float*)d_in[8];
    const float* Wo   = (const float*)d_in[9];
    const float* bo   = (const float*)d_in[10];
    float* out = (float*)d_out;

    char* ws = (char*)d_ws;
    float* BigB    = (float*)(ws + 0);              // 256*768*4       = 786432
    float* BigBias = (float*)(ws + 786432);         // 768*4           -> 789504
    float* BigC    = (float*)(ws + 789504);         // 4096*768*4      -> 13372416
    float* sq      = (float*)(ws + 13372416);       // 4096*4          -> 13388800
    float* e1      = (float*)(ws + 13388800);       // 4*4096*4        -> 13454336
    float* e2      = (float*)(ws + 13454336);       // 4*4096*4        -> 13519872
    float* candD   = (float*)(ws + 13519872);       // 4096*48*4       -> 14306304
    int*   candI   = (int*)  (ws + 14306304);       // 4096*48*4       -> 15092736
    int*   idx6    = (int*)  (ws + 15092736);       // 4096*6*4        -> 15191040

    hipLaunchKernelGGL(repack_kernel, dim3(768), dim3(256), 0, stream,
                       Wm, bm, W, Wr, br, BigB, BigBias);
    hipLaunchKernelGGL(gemm_kernel, dim3(64, 12), dim3(256), 0, stream,
                       x, BigB, BigBias, BigC);
    hipLaunchKernelGGL(sq_e_kernel, dim3(4096), dim3(256), 0, stream,
                       BigC, a, sq, e1, e2);
    hipLaunchKernelGGL(dist_topk_kernel, dim3(64, JSPLIT), dim3(256), 0, stream,
                       BigC, sq, candD, candI);
    hipLaunchKernelGGL(merge_kernel, dim3(16), dim3(256), 0, stream,
                       candD, candI, idx6);
    hipLaunchKernelGGL(final_kernel, dim3(4096), dim3(256), 0, stream,
                       BigC, e1, e2, idx6, ln_g, ln_b, Wo, bo, out);
}